// Round 12
// baseline (1340.979 us; speedup 1.0000x reference)
//
#include <hip/hip_runtime.h>
#include <hip/hip_bf16.h>

// DeBERTa layer: B=16,S=512,H=1024,NH=8,HD=128,FF=3072.
// R20 = R19 + one experiment: dense GEMMs on BK=64 reg-staging with
// __launch_bounds__(256, 2). R17/R18's BK=64 spill was the allocator pinning
// 72 arch-VGPRs (occupancy-targeted heuristic) and pushing the prefetch to
// scratch (790MB WRITE_SIZE); the explicit 2-waves/EU bound raises the
// register budget to 256/wave so the ~150-reg working set fits.
// QK^T/PV stay on the BK=32 batched kernel; middle unchanged from R19.
#define BB  16
#define SS  512
#define HH  1024
#define NHH 8
#define HDD 128
#define FFF 3072
#define TT  (BB * SS)   // 8192 tokens

typedef __hip_bfloat16 bf16;
typedef short s8v __attribute__((ext_vector_type(8)));   // 8 bf16 bits (4 VGPRs)
typedef float f4v __attribute__((ext_vector_type(4)));   // 4 f32 acc

__device__ __forceinline__ float bf2f(bf16 v) { return __bfloat162float(v); }
__device__ __forceinline__ bf16 f2bf(float f) { return __float2bfloat16(f); }
__device__ __forceinline__ float us2f(unsigned short u) {
  union { unsigned int i; float f; } c; c.i = (unsigned int)u << 16; return c.f;
}

// ---------------- Embedding LayerNorm (f32 in -> bf16 out) ----------------------
__global__ void embed_ln_kernel(const float* __restrict__ x, const float* __restrict__ pos,
                                const float* __restrict__ g, const float* __restrict__ bta,
                                bf16* __restrict__ h) {
  int t = blockIdx.x;
  int s = t & (SS - 1);
  int tid = threadIdx.x;
  const float* xr = x + (size_t)t * HH;
  const float* pr = pos + (size_t)s * HH;
  float vals[4];
  float sum = 0.f;
#pragma unroll
  for (int i = 0; i < 4; i++) {
    int c = tid + i * 256;
    vals[i] = xr[c] + pr[c];
    sum += vals[i];
  }
  __shared__ float red[4];
#pragma unroll
  for (int off = 32; off > 0; off >>= 1) sum += __shfl_down(sum, off, 64);
  if ((tid & 63) == 0) red[tid >> 6] = sum;
  __syncthreads();
  float mean = (red[0] + red[1] + red[2] + red[3]) * (1.f / HH);
  float vsum = 0.f;
#pragma unroll
  for (int i = 0; i < 4; i++) { float d = vals[i] - mean; vsum += d * d; }
  __syncthreads();
#pragma unroll
  for (int off = 32; off > 0; off >>= 1) vsum += __shfl_down(vsum, off, 64);
  if ((tid & 63) == 0) red[tid >> 6] = vsum;
  __syncthreads();
  float rstd = rsqrtf((red[0] + red[1] + red[2] + red[3]) * (1.f / HH) + 1e-7f);
  bf16* hr = h + (size_t)t * HH;
#pragma unroll
  for (int i = 0; i < 4; i++) {
    int c = tid + i * 256;
    hr[c] = f2bf((vals[i] - mean) * rstd * g[c] + bta[c]);
  }
}

// ------- a(bf16)+res(bf16) -> LN -> out (OUT_F32 ? float : bf16) ---------------
template <int OUT_F32>
__global__ void add_ln_kernel(const bf16* __restrict__ a, const bf16* __restrict__ res,
                              const float* __restrict__ g, const float* __restrict__ bta,
                              void* __restrict__ outv) {
  int t = blockIdx.x;
  int tid = threadIdx.x;
  const bf16* ar = a + (size_t)t * HH;
  const bf16* rr = res + (size_t)t * HH;
  float vals[4];
  float sum = 0.f;
#pragma unroll
  for (int i = 0; i < 4; i++) {
    int c = tid + i * 256;
    vals[i] = bf2f(ar[c]) + bf2f(rr[c]);
    sum += vals[i];
  }
  __shared__ float red[4];
#pragma unroll
  for (int off = 32; off > 0; off >>= 1) sum += __shfl_down(sum, off, 64);
  if ((tid & 63) == 0) red[tid >> 6] = sum;
  __syncthreads();
  float mean = (red[0] + red[1] + red[2] + red[3]) * (1.f / HH);
  float vsum = 0.f;
#pragma unroll
  for (int i = 0; i < 4; i++) { float d = vals[i] - mean; vsum += d * d; }
  __syncthreads();
#pragma unroll
  for (int off = 32; off > 0; off >>= 1) vsum += __shfl_down(vsum, off, 64);
  if ((tid & 63) == 0) red[tid >> 6] = vsum;
  __syncthreads();
  float rstd = rsqrtf((red[0] + red[1] + red[2] + red[3]) * (1.f / HH) + 1e-7f);
#pragma unroll
  for (int i = 0; i < 4; i++) {
    int c = tid + i * 256;
    float o = (vals[i] - mean) * rstd * g[c] + bta[c];
    if (OUT_F32)
      ((float*)outv)[(size_t)t * HH + c] = o;
    else
      ((bf16*)outv)[(size_t)t * HH + c] = f2bf(o);
  }
}

// ---- weight convert+transpose: W[K,N] f32 -> Wt[N,K] bf16 (K fixed per call) --
__global__ void convert_w_kernel(const float* __restrict__ W, bf16* __restrict__ Wt,
                                 int K, int N) {
  __shared__ float tile[32][33];
  int n0 = blockIdx.x * 32, k0 = blockIdx.y * 32;
#pragma unroll
  for (int it = 0; it < 4; it++) {
    int idx = threadIdx.x + it * 256;
    int ty = idx >> 5, tx = idx & 31;
    tile[ty][tx] = W[(size_t)(k0 + ty) * N + n0 + tx];
  }
  __syncthreads();
#pragma unroll
  for (int it = 0; it < 4; it++) {
    int idx = threadIdx.x + it * 256;
    int ty = idx >> 5, tx = idx & 31;
    Wt[(size_t)(n0 + ty) * K + k0 + tx] = f2bf(tile[tx][ty]);
  }
}

// ---- concat qkv bias: [qbias | 0 | vbias] (f32) -------------------------------
__global__ void build_qkv_bias_kernel(const float* __restrict__ qb,
                                      const float* __restrict__ vb,
                                      float* __restrict__ o) {
  int i = blockIdx.x * 256 + threadIdx.x;  // 0..3071
  float v = 0.f;
  if (i < HH) v = qb[i];
  else if (i >= 2 * HH) v = vb[i - 2 * HH];
  o[i] = v;
}

// ---- V transpose per head: qkv v-cols -> vt[b,h,dim,key] (bf16) ---------------
__global__ void transpose_v_kernel(const bf16* __restrict__ v, bf16* __restrict__ vt) {
  __shared__ unsigned short tile[32][33];
  int bh = blockIdx.z;
  int s0 = blockIdx.x * 32, d0 = blockIdx.y * 32;
  int b = bh >> 3, hd = bh & 7;
  const unsigned short* vp = (const unsigned short*)v + ((size_t)b * SS) * (3 * HH) + hd * HDD;
  unsigned short* vtp = (unsigned short*)vt + (size_t)bh * HDD * SS;
#pragma unroll
  for (int it = 0; it < 4; it++) {
    int idx = threadIdx.x + it * 256;
    int ty = idx >> 5, tx = idx & 31;
    tile[ty][tx] = vp[(size_t)(s0 + ty) * (3 * HH) + d0 + tx];
  }
  __syncthreads();
#pragma unroll
  for (int it = 0; it < 4; it++) {
    int idx = threadIdx.x + it * 256;
    int ty = idx >> 5, tx = idx & 31;
    vtp[(size_t)(d0 + ty) * SS + s0 + tx] = tile[tx][ty];
  }
}

// ---- V1: 128x128 MFMA GEMM (batched QK^T / PV), BK=32 reg-staging -------------
template <int GELU>
__global__ __launch_bounds__(256)
void mfma_gemm_kernel(const bf16* __restrict__ A, int lda, long long sAb, long long sAh,
                      const bf16* __restrict__ Bt, int ldb, long long sBb, long long sBh,
                      const float* __restrict__ bias,
                      bf16* __restrict__ C, int ldc, long long sCb, long long sCh,
                      int M, int N, int K, float scale) {
  __shared__ __align__(16) unsigned short Als[128 * 32];
  __shared__ __align__(16) unsigned short Bls[128 * 32];
  int tid = threadIdx.x;
  int lane = tid & 63, wave = tid >> 6;
  int l15 = lane & 15, quad = lane >> 4;
  int wm = wave & 1, wn = wave >> 1;
  int m0 = blockIdx.y * 128, n0 = blockIdx.x * 128;
  int zb = blockIdx.z >> 3, zh = blockIdx.z & 7;
  const bf16* Ab = A + zb * sAb + zh * sAh;
  const bf16* Bb = Bt + zb * sBb + zh * sBh;
  bf16* Cb = C + zb * sCb + zh * sCh;
  f4v acc[4][4];
#pragma unroll
  for (int i = 0; i < 4; i++)
#pragma unroll
    for (int j = 0; j < 4; j++) acc[i][j] = (f4v){0.f, 0.f, 0.f, 0.f};
  int r0 = tid >> 2;            // 0..63: staging rows r0, r0+64
  int q8 = (tid & 3) * 8;       // global 16B chunk offset (coalesced)
  int fw = (r0 >> 1) & 3;
  int wlo = r0 * 32 + (((tid & 3) ^ fw) * 8);
  int whi = (r0 + 64) * 32 + (((tid & 3) ^ fw) * 8);
  int qx = (quad ^ ((l15 >> 1) & 3)) * 8;
  const bf16* Ap0 = Ab + (size_t)(m0 + r0) * lda + q8;
  const bf16* Ap1 = Ab + (size_t)(m0 + r0 + 64) * lda + q8;
  const bf16* Bp0 = Bb + (size_t)(n0 + r0) * ldb + q8;
  const bf16* Bp1 = Bb + (size_t)(n0 + r0 + 64) * ldb + q8;
  uint4 a0 = *(const uint4*)(Ap0);
  uint4 a1 = *(const uint4*)(Ap1);
  uint4 b0 = *(const uint4*)(Bp0);
  uint4 b1 = *(const uint4*)(Bp1);
  for (int k0 = 0; k0 < K; k0 += 32) {
    *(uint4*)&Als[wlo] = a0;
    *(uint4*)&Als[whi] = a1;
    *(uint4*)&Bls[wlo] = b0;
    *(uint4*)&Bls[whi] = b1;
    __syncthreads();
    int kn = k0 + 32;
    if (kn < K) {           // issue next tile's loads; in flight during MFMAs
      a0 = *(const uint4*)(Ap0 + kn);
      a1 = *(const uint4*)(Ap1 + kn);
      b0 = *(const uint4*)(Bp0 + kn);
      b1 = *(const uint4*)(Bp1 + kn);
    }
    s8v af[4], bfr[4];
#pragma unroll
    for (int i = 0; i < 4; i++)
      af[i] = *(const s8v*)&Als[(wm * 64 + i * 16 + l15) * 32 + qx];
#pragma unroll
    for (int j = 0; j < 4; j++)
      bfr[j] = *(const s8v*)&Bls[(wn * 64 + j * 16 + l15) * 32 + qx];
#pragma unroll
    for (int i = 0; i < 4; i++)
#pragma unroll
      for (int j = 0; j < 4; j++)
        acc[i][j] = __builtin_amdgcn_mfma_f32_16x16x32_bf16(af[i], bfr[j], acc[i][j], 0, 0, 0);
    __syncthreads();
  }
#pragma unroll
  for (int i = 0; i < 4; i++) {
#pragma unroll
    for (int j = 0; j < 4; j++) {
      int n = n0 + wn * 64 + j * 16 + l15;
      float bval = bias ? bias[n] : 0.f;
#pragma unroll
      for (int r = 0; r < 4; r++) {
        int m = m0 + wm * 64 + i * 16 + quad * 4 + r;
        float v = (acc[i][j][r] + bval) * scale;
        if (GELU) v = 0.5f * v * (1.f + erff(v * 0.70710678118654752f));
        Cb[(size_t)m * ldc + n] = f2bf(v);
      }
    }
  }
}

// ---- gemm64: 128x128 dense GEMM, BK=64 reg-staging, launch_bounds(256,2) ------
// R18's correctness-verified BK=64 body (sequential k-subtiles) with the
// register budget raised to 256/wave (2 waves/EU) so the 8-uint4 prefetch
// stays in registers (R17/R18 spilled at the default occupancy target).
// 32 MFMA per barrier-pair, half the barriers of BK=32. LDS [128][64]/op,
// chunk c of row r at c ^ (r&7) (write via global-col permutation).
template <int GELU>
__global__ __launch_bounds__(256, 2)
void gemm64_kernel(const bf16* __restrict__ A, int lda,
                   const bf16* __restrict__ Bt, int ldb,
                   const float* __restrict__ bias,
                   bf16* __restrict__ C, int ldc,
                   int M, int N, int K, float scale) {
  __shared__ __align__(16) unsigned short Als[128 * 64];
  __shared__ __align__(16) unsigned short Bls[128 * 64];
  int tid = threadIdx.x;
  int lane = tid & 63, wave = tid >> 6;
  int l15 = lane & 15, quad = lane >> 4;
  int wm = wave & 1, wn = wave >> 1;
  int m0 = blockIdx.y * 128, n0 = blockIdx.x * 128;
  f4v acc[4][4];
#pragma unroll
  for (int i = 0; i < 4; i++)
#pragma unroll
    for (int j = 0; j < 4; j++) acc[i][j] = (f4v){0.f, 0.f, 0.f, 0.f};

  int r0 = tid >> 3;            // base staging row 0..31 (segments +32,+64,+96)
  int c0 = tid & 7;             // global 16B chunk within the 64-col k-tile
  int wcol = ((c0 ^ (r0 & 7)) * 8);   // swizzled LDS col ((r0+32s)&7 == r0&7)
  const bf16* Apb = A + (size_t)(m0 + r0) * lda + c0 * 8;
  const bf16* Bpb = Bt + (size_t)(n0 + r0) * ldb + c0 * 8;
  uint4 abuf[4], bbuf[4];
#pragma unroll
  for (int s = 0; s < 4; s++) {
    abuf[s] = *(const uint4*)(Apb + (size_t)(s * 32) * lda);
    bbuf[s] = *(const uint4*)(Bpb + (size_t)(s * 32) * ldb);
  }
  int xr = l15 & 7;
  for (int k0 = 0; k0 < K; k0 += 64) {
#pragma unroll
    for (int s = 0; s < 4; s++) {
      *(uint4*)&Als[(r0 + s * 32) * 64 + wcol] = abuf[s];
      *(uint4*)&Bls[(r0 + s * 32) * 64 + wcol] = bbuf[s];
    }
    __syncthreads();
    int kn = k0 + 64;
    if (kn < K) {            // next-tile loads in flight during ds_read+MFMA
#pragma unroll
      for (int s = 0; s < 4; s++) {
        abuf[s] = *(const uint4*)(Apb + (size_t)(s * 32) * lda + kn);
        bbuf[s] = *(const uint4*)(Bpb + (size_t)(s * 32) * ldb + kn);
      }
    }
    // k-subtile 0
    {
      s8v af[4], bfr[4];
#pragma unroll
      for (int i = 0; i < 4; i++)
        af[i] = *(const s8v*)&Als[(wm * 64 + i * 16 + l15) * 64 + ((quad ^ xr) * 8)];
#pragma unroll
      for (int j = 0; j < 4; j++)
        bfr[j] = *(const s8v*)&Bls[(wn * 64 + j * 16 + l15) * 64 + ((quad ^ xr) * 8)];
#pragma unroll
      for (int i = 0; i < 4; i++)
#pragma unroll
        for (int j = 0; j < 4; j++)
          acc[i][j] = __builtin_amdgcn_mfma_f32_16x16x32_bf16(af[i], bfr[j], acc[i][j], 0, 0, 0);
    }
    // k-subtile 1
    {
      s8v af[4], bfr[4];
#pragma unroll
      for (int i = 0; i < 4; i++)
        af[i] = *(const s8v*)&Als[(wm * 64 + i * 16 + l15) * 64 + (((4 + quad) ^ xr) * 8)];
#pragma unroll
      for (int j = 0; j < 4; j++)
        bfr[j] = *(const s8v*)&Bls[(wn * 64 + j * 16 + l15) * 64 + (((4 + quad) ^ xr) * 8)];
#pragma unroll
      for (int i = 0; i < 4; i++)
#pragma unroll
        for (int j = 0; j < 4; j++)
          acc[i][j] = __builtin_amdgcn_mfma_f32_16x16x32_bf16(af[i], bfr[j], acc[i][j], 0, 0, 0);
    }
    __syncthreads();
  }
#pragma unroll
  for (int i = 0; i < 4; i++) {
#pragma unroll
    for (int j = 0; j < 4; j++) {
      int n = n0 + wn * 64 + j * 16 + l15;
      float bval = bias ? bias[n] : 0.f;
#pragma unroll
      for (int r = 0; r < 4; r++) {
        int m = m0 + wm * 64 + i * 16 + quad * 4 + r;
        float v = (acc[i][j][r] + bval) * scale;
        if (GELU) v = 0.5f * v * (1.f + erff(v * 0.70710678118654752f));
        C[(size_t)m * ldc + n] = f2bf(v);
      }
    }
  }
}

// ---- softmax over last dim of scores [128*512 rows][512], bf16 in-place -------
__global__ void softmax_kernel(bf16* __restrict__ sc) {
  int wave = threadIdx.x >> 6, lane = threadIdx.x & 63;
  size_t row = (size_t)blockIdx.x * 4 + wave;
  unsigned short* p = (unsigned short*)sc + row * SS + lane * 8;
  union { uint4 u4; unsigned short u[8]; } buf;
  buf.u4 = *(const uint4*)p;
  float v[8];
  float mx = -1e30f;
#pragma unroll
  for (int j = 0; j < 8; j++) { v[j] = us2f(buf.u[j]); mx = fmaxf(mx, v[j]); }
#pragma unroll
  for (int off = 32; off > 0; off >>= 1) mx = fmaxf(mx, __shfl_xor(mx, off));
  float sum = 0.f;
#pragma unroll
  for (int j = 0; j < 8; j++) { v[j] = __expf(v[j] - mx); sum += v[j]; }
#pragma unroll
  for (int off = 32; off > 0; off >>= 1) sum += __shfl_xor(sum, off);
  float inv = 1.f / sum;
  union { uint4 u4; unsigned short u[8]; } obuf;
#pragma unroll
  for (int j = 0; j < 8; j++) {
    bf16 b = f2bf(v[j] * inv);
    obuf.u[j] = *(unsigned short*)&b;
  }
  *(uint4*)p = obuf.u4;
}

// ---------------- launch ----------------
extern "C" void kernel_launch(void* const* d_in, const int* in_sizes, int n_in,
                              void* d_out, int out_size, void* d_ws, size_t ws_size,
                              hipStream_t stream) {
  const float* x     = (const float*)d_in[0];
  const float* pos   = (const float*)d_in[1];
  const float* eg    = (const float*)d_in[2];
  const float* ebeta = (const float*)d_in[3];
  const float* Wq    = (const float*)d_in[4];
  const float* Wk    = (const float*)d_in[5];
  const float* Wv    = (const float*)d_in[6];
  const float* qbias = (const float*)d_in[7];
  const float* vbias = (const float*)d_in[8];
  const float* Wo    = (const float*)d_in[9];
  const float* bo    = (const float*)d_in[10];
  const float* l1g   = (const float*)d_in[11];
  const float* l1b   = (const float*)d_in[12];
  const float* Wi    = (const float*)d_in[13];
  const float* bi    = (const float*)d_in[14];
  const float* Wf    = (const float*)d_in[15];
  const float* bfb   = (const float*)d_in[16];
  const float* l2g   = (const float*)d_in[17];
  const float* l2b   = (const float*)d_in[18];

  // --- workspace (256 MiB): [MiB offsets] ---
  char* w = (char*)d_ws;
  const size_t MB = (size_t)1 << 20;
  bf16* h      = (bf16*)(w + 0 * MB);     // 16
  bf16* qkv    = (bf16*)(w + 16 * MB);    // 48: [T][3H] fused q|k|v
  bf16* ctx    = (bf16*)(w + 64 * MB);    // 16
  bf16* tmp1   = (bf16*)(w + 80 * MB);    // 16
  bf16* attn   = (bf16*)(w + 96 * MB);    // 16
  bf16* scores = (bf16*)(w + 112 * MB);   // 64 [112,176) live: qk->pv
  bf16* ff     = (bf16*)(w + 112 * MB);   // 48 [112,160) live: Wi->Wf (disjoint)
  bf16* tmp2   = (bf16*)(w + 176 * MB);   // 16
  bf16* vt     = (bf16*)(w + 192 * MB);   // 16
  bf16* Wqkvt  = (bf16*)(w + 208 * MB);   // 6: [3H][H] packed q|k|v rows
  bf16* Wot    = (bf16*)(w + 214 * MB);   // 2
  bf16* Wit    = (bf16*)(w + 216 * MB);   // 6
  bf16* Wft    = (bf16*)(w + 222 * MB);   // 6
  float* qkvb  = (float*)(w + 228 * MB);  // 12 KB
  float* out   = (float*)d_out;

  const float QSCALE = 0.08838834764831845f;  // 1/sqrt(128), applied in QK epilogue

  embed_ln_kernel<<<TT, 256, 0, stream>>>(x, pos, eg, ebeta, h);

  convert_w_kernel<<<dim3(HH / 32, HH / 32), 256, 0, stream>>>(Wq, Wqkvt, HH, HH);
  convert_w_kernel<<<dim3(HH / 32, HH / 32), 256, 0, stream>>>(Wk, Wqkvt + (size_t)HH * HH, HH, HH);
  convert_w_kernel<<<dim3(HH / 32, HH / 32), 256, 0, stream>>>(Wv, Wqkvt + (size_t)2 * HH * HH, HH, HH);
  convert_w_kernel<<<dim3(HH / 32, HH / 32), 256, 0, stream>>>(Wo, Wot, HH, HH);
  convert_w_kernel<<<dim3(FFF / 32, HH / 32), 256, 0, stream>>>(Wi, Wit, HH, FFF);
  convert_w_kernel<<<dim3(HH / 32, FFF / 32), 256, 0, stream>>>(Wf, Wft, FFF, HH);
  build_qkv_bias_kernel<<<12, 256, 0, stream>>>(qbias, vbias, qkvb);

  // fused QKV: qkv[8192,3072] = h @ Wqkvt^T + qkvb   (BK=64, launch_bounds(256,2))
  gemm64_kernel<0><<<dim3(24, 64), 256, 0, stream>>>(
      h, HH, Wqkvt, HH, qkvb, qkv, 3 * HH, TT, 3 * HH, HH, 1.f);

  // scores[b,h,512,512] = (q_bh @ k_bh^T) * QSCALE  (k cols of qkv act as Bt)
  mfma_gemm_kernel<0><<<dim3(4, 4, BB * NHH), 256, 0, stream>>>(
      qkv, 3 * HH, (long long)SS * 3 * HH, HDD,
      qkv + HH, 3 * HH, (long long)SS * 3 * HH, HDD,
      nullptr,
      scores, SS, (long long)NHH * SS * SS, (long long)SS * SS,
      SS, SS, HDD, QSCALE);

  softmax_kernel<<<BB * NHH * SS / 4, 256, 0, stream>>>(scores);

  transpose_v_kernel<<<dim3(SS / 32, HDD / 32, BB * NHH), 256, 0, stream>>>(qkv + 2 * HH, vt);

  // ctx_bh[512,128] = probs_bh @ v_bh  (vt[dim][key] is Bt layout)
  mfma_gemm_kernel<0><<<dim3(1, 4, BB * NHH), 256, 0, stream>>>(
      scores, SS, (long long)NHH * SS * SS, (long long)SS * SS,
      vt, SS, (long long)NHH * HDD * SS, (long long)HDD * SS,
      nullptr,
      ctx, HH, (long long)SS * HH, HDD,
      SS, HDD, SS, 1.f);

  gemm64_kernel<0><<<dim3(8, 64), 256, 0, stream>>>(
      ctx, HH, Wot, HH, bo, tmp1, HH, TT, HH, HH, 1.f);
  add_ln_kernel<0><<<TT, 256, 0, stream>>>(tmp1, h, l1g, l1b, attn);

  gemm64_kernel<1><<<dim3(24, 64), 256, 0, stream>>>(
      attn, HH, Wit, HH, bi, ff, FFF, TT, FFF, HH, 1.f);
  gemm64_kernel<0><<<dim3(8, 64), 256, 0, stream>>>(
      ff, FFF, Wft, FFF, bfb, tmp2, HH, TT, HH, FFF, 1.f);
  add_ln_kernel<1><<<TT, 256, 0, stream>>>(tmp2, attn, l2g, l2b, out);
}